// Round 1
// baseline (474.593 us; speedup 1.0000x reference)
//
#include <hip/hip_runtime.h>
#include <hip/hip_bf16.h>

typedef unsigned short u16;
typedef __attribute__((ext_vector_type(8))) short bf16x8;
typedef __attribute__((ext_vector_type(4))) float f32x4;

#define B_  4
#define T_  2048
#define C_  1024
#define H_  16
#define DH_ 64
#define M_  (B_*T_)   // 8192

__device__ __forceinline__ u16 f2b(float f) {
  union { __hip_bfloat16 h; u16 u; } cv;
  cv.h = __float2bfloat16(f);
  return cv.u;
}

// ---------------- fp32 -> bf16 cast, 4 elems/thread ----------------
__global__ void cast_bf16_kernel(const float* __restrict__ in, u16* __restrict__ out, int n) {
  int i = (blockIdx.x * blockDim.x + threadIdx.x) * 4;
  if (i >= n) return;
  float4 v = *(const float4*)(in + i);
  unsigned lo = (unsigned)f2b(v.x) | ((unsigned)f2b(v.y) << 16);
  unsigned hi = (unsigned)f2b(v.z) | ((unsigned)f2b(v.w) << 16);
  uint2 p; p.x = lo; p.y = hi;
  *(uint2*)(out + i) = p;
}

// ---------------- GEMM: C[m,n] = sum_k A[m,k] * B[n,k]  (B row-major [N,K]) ----------------
// 128x128 tile, BK=32, 4 waves, each wave 64x64 (4x4 tiles of 16x16x32 MFMA).
// mode 0: write bf16 scattered to [B, H2=32, T, Dh] (Q then V halves, N=2048)
// mode 1: write fp32 row-major [M, 1024]
__global__ __launch_bounds__(256) void gemm_bt_kernel(
    const u16* __restrict__ A, const u16* __restrict__ Bm,
    void* __restrict__ Cout, int mode)
{
  constexpr int K   = 1024;
  constexpr int LDK = 40;                 // 32 + 8 pad: 80B rows, 16B-aligned, 2-way-conflict free
  __shared__ __align__(16) u16 As[128 * LDK];
  __shared__ __align__(16) u16 Bs[128 * LDK];

  const int tid  = threadIdx.x;
  const int wave = tid >> 6, lane = tid & 63;
  const int quad = lane >> 4, l15 = lane & 15;
  const int wm = (wave >> 1) * 64, wn = (wave & 1) * 64;
  const int tm = blockIdx.x * 128, tn = blockIdx.y * 128;

  f32x4 acc[4][4] = {};

  for (int k0 = 0; k0 < K; k0 += 32) {
    // stage 128x32 A and B tiles: 512 16B-chunks each, 2 per thread
#pragma unroll
    for (int i = 0; i < 2; i++) {
      int c = tid + i * 256;
      int row = c >> 2, col = (c & 3) * 8;
      *(uint4*)(&As[row * LDK + col]) = *(const uint4*)(A  + (size_t)(tm + row) * K + k0 + col);
      *(uint4*)(&Bs[row * LDK + col]) = *(const uint4*)(Bm + (size_t)(tn + row) * K + k0 + col);
    }
    __syncthreads();

    bf16x8 af[4], bfr[4];
#pragma unroll
    for (int t = 0; t < 4; t++) {
      af[t]  = *(const bf16x8*)(&As[(wm + t * 16 + l15) * LDK + quad * 8]);
      bfr[t] = *(const bf16x8*)(&Bs[(wn + t * 16 + l15) * LDK + quad * 8]);
    }
#pragma unroll
    for (int mt = 0; mt < 4; mt++)
#pragma unroll
      for (int nt = 0; nt < 4; nt++)
        acc[mt][nt] = __builtin_amdgcn_mfma_f32_16x16x32_bf16(af[mt], bfr[nt], acc[mt][nt], 0, 0, 0);
    __syncthreads();
  }

  // epilogue: C/D layout col=lane&15, row=quad*4+reg
  if (mode == 0) {
    u16* out = (u16*)Cout;
#pragma unroll
    for (int mt = 0; mt < 4; mt++)
#pragma unroll
      for (int nt = 0; nt < 4; nt++)
#pragma unroll
        for (int r = 0; r < 4; r++) {
          int gm = tm + wm + mt * 16 + quad * 4 + r;
          int gn = tn + wn + nt * 16 + l15;
          int b = gm >> 11, t = gm & 2047;
          int h2 = gn >> 6, d = gn & 63;
          // Q area (h2<16) then V area (h2>=16); V base offset = 4*16*2048*64 elems
          size_t idx = (size_t)(h2 >> 4) * 8388608
                     + ((size_t)((b * 16 + (h2 & 15)) * 2048 + t) << 6) + d;
          out[idx] = f2b(acc[mt][nt][r]);
        }
  } else {
    float* out = (float*)Cout;
#pragma unroll
    for (int mt = 0; mt < 4; mt++)
#pragma unroll
      for (int nt = 0; nt < 4; nt++)
#pragma unroll
        for (int r = 0; r < 4; r++) {
          int gm = tm + wm + mt * 16 + quad * 4 + r;
          int gn = tn + wn + nt * 16 + l15;
          out[(size_t)gm * 1024 + gn] = acc[mt][nt][r];
        }
  }
}

// ---------------- causal flash attention, K==Q (reference bug), bf16 MFMA ----------------
// grid (16 qblocks, 64 b*h); block 256 = 4 waves; wave owns 32 q-rows; key tiles of 64.
__global__ __launch_bounds__(256) void attn_kernel(
    const u16* __restrict__ Q, const u16* __restrict__ V, u16* __restrict__ AO)
{
  constexpr int LD = 72;  // 64 + 8 pad, 144B rows (16B aligned)
  __shared__ __align__(16) u16 Ks[64 * LD];       // [key][dh]
  __shared__ __align__(16) u16 Vts[64 * LD];      // [dh][key] (transposed)
  __shared__ __align__(16) u16 Ps[4][32 * LD];    // per-wave P in [row][key]

  const int tid  = threadIdx.x;
  const int wave = tid >> 6, lane = tid & 63;
  const int quad = lane >> 4, l15 = lane & 15;
  const int qb = blockIdx.x, bh = blockIdx.y;
  const u16* Qbh = Q + (size_t)bh * (T_ * DH_);
  const u16* Vbh = V + (size_t)bh * (T_ * DH_);
  const int q0 = qb * 128 + wave * 32;

  // Q fragments for the wave's 32 rows, held in registers for all k-blocks
  bf16x8 qf[2][2];
#pragma unroll
  for (int mt = 0; mt < 2; mt++)
#pragma unroll
    for (int ks = 0; ks < 2; ks++)
      qf[mt][ks] = *(const bf16x8*)(Qbh + (size_t)(q0 + mt * 16 + l15) * DH_ + ks * 32 + quad * 8);

  f32x4 o[2][4] = {};
  float mrow[2][4], lrow[2][4];
#pragma unroll
  for (int mt = 0; mt < 2; mt++)
#pragma unroll
    for (int r = 0; r < 4; r++) { mrow[mt][r] = -INFINITY; lrow[mt][r] = 0.f; }

  const int nkb = 2 * qb + 2;  // causal: only K-blocks touching the lower triangle
  for (int kb = 0; kb < nkb; kb++) {
    const int k0 = kb * 64;
    // stage K tile (as-is) and V tile (transposed) into LDS
#pragma unroll
    for (int i = 0; i < 2; i++) {
      int c = tid + i * 256;            // 0..511
      int row = c >> 3, col = (c & 7) * 8;
      *(uint4*)(&Ks[row * LD + col]) = *(const uint4*)(Qbh + (size_t)(k0 + row) * DH_ + col);
      uint4 vv = *(const uint4*)(Vbh + (size_t)(k0 + row) * DH_ + col);
      const u16* ep = (const u16*)&vv;
#pragma unroll
      for (int j = 0; j < 8; j++) Vts[(col + j) * LD + row] = ep[j];
    }
    __syncthreads();

    // S = Q K^T  (2 m-tiles x 4 n-tiles x 2 k-steps)
    f32x4 s[2][4] = {};
#pragma unroll
    for (int nt = 0; nt < 4; nt++)
#pragma unroll
      for (int ks = 0; ks < 2; ks++) {
        bf16x8 kf = *(const bf16x8*)(&Ks[(nt * 16 + l15) * LD + ks * 32 + quad * 8]);
#pragma unroll
        for (int mt = 0; mt < 2; mt++)
          s[mt][nt] = __builtin_amdgcn_mfma_f32_16x16x32_bf16(qf[mt][ks], kf, s[mt][nt], 0, 0, 0);
      }

    // scale 1/sqrt(64) + causal mask (only needed on diagonal tiles)
    const bool diag = (k0 + 63 > q0);
#pragma unroll
    for (int mt = 0; mt < 2; mt++)
#pragma unroll
      for (int nt = 0; nt < 4; nt++)
#pragma unroll
        for (int r = 0; r < 4; r++) {
          float v = s[mt][nt][r] * 0.125f;
          if (diag) {
            int qg = q0 + mt * 16 + quad * 4 + r;
            int kg = k0 + nt * 16 + l15;
            v = (kg <= qg) ? v : -INFINITY;
          }
          s[mt][nt][r] = v;
        }

    // online softmax: rows live in 16-lane groups (fixed quad), cols = lane&15
#pragma unroll
    for (int mt = 0; mt < 2; mt++)
#pragma unroll
      for (int r = 0; r < 4; r++) {
        float mx = fmaxf(fmaxf(s[mt][0][r], s[mt][1][r]), fmaxf(s[mt][2][r], s[mt][3][r]));
#pragma unroll
        for (int off = 1; off < 16; off <<= 1) mx = fmaxf(mx, __shfl_xor(mx, off, 64));
        float mnew  = fmaxf(mrow[mt][r], mx);
        float alpha = exp2f((mrow[mt][r] - mnew) * 1.44269504f);
        float sum = 0.f;
#pragma unroll
        for (int nt = 0; nt < 4; nt++) {
          float p = exp2f((s[mt][nt][r] - mnew) * 1.44269504f);
          s[mt][nt][r] = p;
          sum += p;
        }
#pragma unroll
        for (int off = 1; off < 16; off <<= 1) sum += __shfl_xor(sum, off, 64);
        lrow[mt][r] = lrow[mt][r] * alpha + sum;
        mrow[mt][r] = mnew;
#pragma unroll
        for (int dt = 0; dt < 4; dt++) o[mt][dt][r] *= alpha;
      }

    // P: C-layout regs -> A-layout via per-wave LDS round-trip
    u16* myP = &Ps[wave][0];
#pragma unroll
    for (int mt = 0; mt < 2; mt++)
#pragma unroll
      for (int nt = 0; nt < 4; nt++)
#pragma unroll
        for (int r = 0; r < 4; r++)
          myP[(mt * 16 + quad * 4 + r) * LD + nt * 16 + l15] = f2b(s[mt][nt][r]);

    __syncthreads();

    // O += P V   (A = P [32 x 64keys], B = V [64keys x 64dh] via Vts)
#pragma unroll
    for (int ks2 = 0; ks2 < 2; ks2++) {
      bf16x8 pf[2];
#pragma unroll
      for (int mt = 0; mt < 2; mt++)
        pf[mt] = *(const bf16x8*)(&myP[(mt * 16 + l15) * LD + ks2 * 32 + quad * 8]);
#pragma unroll
      for (int dt = 0; dt < 4; dt++) {
        bf16x8 vf = *(const bf16x8*)(&Vts[(dt * 16 + l15) * LD + ks2 * 32 + quad * 8]);
#pragma unroll
        for (int mt = 0; mt < 2; mt++)
          o[mt][dt] = __builtin_amdgcn_mfma_f32_16x16x32_bf16(pf[mt], vf, o[mt][dt], 0, 0, 0);
      }
    }
    __syncthreads();
  }

  // epilogue: O/l -> bf16, layout [B, T, H*Dh] for the output projection GEMM
  const int b = bh >> 4, h = bh & 15;
#pragma unroll
  for (int mt = 0; mt < 2; mt++)
#pragma unroll
    for (int r = 0; r < 4; r++) {
      float rl = 1.0f / lrow[mt][r];
      int t = q0 + mt * 16 + quad * 4 + r;
#pragma unroll
      for (int dt = 0; dt < 4; dt++)
        AO[((size_t)(b * T_ + t)) * C_ + h * DH_ + dt * 16 + l15] = f2b(o[mt][dt][r] * rl);
    }
}

extern "C" void kernel_launch(void* const* d_in, const int* in_sizes, int n_in,
                              void* d_out, int out_size, void* d_ws, size_t ws_size,
                              hipStream_t stream) {
  (void)in_sizes; (void)n_in; (void)out_size; (void)ws_size;
  const float* x  = (const float*)d_in[0];
  const float* Wq = (const float*)d_in[1];
  // d_in[2] = W_k is unused (reference bug: K uses W_q)
  const float* Wv = (const float*)d_in[3];
  const float* Wo = (const float*)d_in[4];

  // workspace layout (u16 elements)
  u16* Xb  = (u16*)d_ws;            // 8388608  : x as bf16 [8192,1024]
  u16* Wqb = Xb  + 8388608;         // 1048576  : W_q bf16 [1024,1024]
  u16* Wvb = Wqb + 1048576;         // 1048576  : W_v bf16 (adjacent -> fused N=2048 GEMM)
  u16* Wob = Wvb + 1048576;         // 1048576  : W_o bf16
  u16* Qw  = Wob + 1048576;         // 8388608  : Q [B,H,T,Dh] bf16
  u16* Vw  = Qw  + 8388608;         // 8388608  : V [B,H,T,Dh] bf16 (adjacent to Q)
  u16* AOw = Vw  + 8388608;         // 8388608  : attn out [B,T,C] bf16
  // total 73,400,320 bytes

  cast_bf16_kernel<<<8192, 256, 0, stream>>>(x,  Xb,  8388608);
  cast_bf16_kernel<<<1024, 256, 0, stream>>>(Wq, Wqb, 1048576);
  cast_bf16_kernel<<<1024, 256, 0, stream>>>(Wv, Wvb, 1048576);
  cast_bf16_kernel<<<1024, 256, 0, stream>>>(Wo, Wob, 1048576);

  // fused Q+V projection: B = [Wq; Wv] (2048 x 1024), scatter epilogue
  gemm_bt_kernel<<<dim3(64, 16), 256, 0, stream>>>(Xb, Wqb, (void*)Qw, 0);

  attn_kernel<<<dim3(16, 64), 256, 0, stream>>>(Qw, Vw, AOw);

  // output projection -> fp32 d_out
  gemm_bt_kernel<<<dim3(64, 8), 256, 0, stream>>>(AOw, Wob, d_out, 1);
}

// Round 2
// 312.418 us; speedup vs baseline: 1.5191x; 1.5191x over previous
//
#include <hip/hip_runtime.h>
#include <hip/hip_bf16.h>

typedef unsigned short u16;
typedef __attribute__((ext_vector_type(8))) short bf16x8;
typedef __attribute__((ext_vector_type(4))) float f32x4;

#define B_  4
#define T_  2048
#define C_  1024
#define H_  16
#define DH_ 64
#define M_  (B_*T_)   // 8192

__device__ __forceinline__ u16 f2b(float f) {
  union { __hip_bfloat16 h; u16 u; } cv;
  cv.h = __float2bfloat16(f);
  return cv.u;
}

// ---------------- fp32 -> bf16 cast, 4 elems/thread ----------------
__global__ void cast_bf16_kernel(const float* __restrict__ in, u16* __restrict__ out, int n) {
  int i = (blockIdx.x * blockDim.x + threadIdx.x) * 4;
  if (i >= n) return;
  float4 v = *(const float4*)(in + i);
  unsigned lo = (unsigned)f2b(v.x) | ((unsigned)f2b(v.y) << 16);
  unsigned hi = (unsigned)f2b(v.z) | ((unsigned)f2b(v.w) << 16);
  uint2 p; p.x = lo; p.y = hi;
  *(uint2*)(out + i) = p;
}

// ---------------- GEMM: C[m,n] = sum_k A[m,k] * B[n,k]  (B row-major [N,K]) ----------------
// 128x128 tile, BK=32, 4 waves, each wave 64x64 (4x4 tiles of 16x16x32 MFMA).
// mode 0: write bf16 scattered to [B, H2=32, T, Dh] (Q then V halves, N=2048)
// mode 1: write fp32 row-major [M, 1024]
__global__ __launch_bounds__(256) void gemm_bt_kernel(
    const u16* __restrict__ A, const u16* __restrict__ Bm,
    void* __restrict__ Cout, int mode)
{
  constexpr int K   = 1024;
  constexpr int LDK = 40;                 // 32 + 8 pad: 80B rows, 16B-aligned, 2-way-conflict free
  __shared__ __align__(16) u16 As[128 * LDK];
  __shared__ __align__(16) u16 Bs[128 * LDK];

  const int tid  = threadIdx.x;
  const int wave = tid >> 6, lane = tid & 63;
  const int quad = lane >> 4, l15 = lane & 15;
  const int wm = (wave >> 1) * 64, wn = (wave & 1) * 64;
  const int tm = blockIdx.x * 128, tn = blockIdx.y * 128;

  f32x4 acc[4][4] = {};

  for (int k0 = 0; k0 < K; k0 += 32) {
#pragma unroll
    for (int i = 0; i < 2; i++) {
      int c = tid + i * 256;
      int row = c >> 2, col = (c & 3) * 8;
      *(uint4*)(&As[row * LDK + col]) = *(const uint4*)(A  + (size_t)(tm + row) * K + k0 + col);
      *(uint4*)(&Bs[row * LDK + col]) = *(const uint4*)(Bm + (size_t)(tn + row) * K + k0 + col);
    }
    __syncthreads();

    bf16x8 af[4], bfr[4];
#pragma unroll
    for (int t = 0; t < 4; t++) {
      af[t]  = *(const bf16x8*)(&As[(wm + t * 16 + l15) * LDK + quad * 8]);
      bfr[t] = *(const bf16x8*)(&Bs[(wn + t * 16 + l15) * LDK + quad * 8]);
    }
#pragma unroll
    for (int mt = 0; mt < 4; mt++)
#pragma unroll
      for (int nt = 0; nt < 4; nt++)
        acc[mt][nt] = __builtin_amdgcn_mfma_f32_16x16x32_bf16(af[mt], bfr[nt], acc[mt][nt], 0, 0, 0);
    __syncthreads();
  }

  if (mode == 0) {
    u16* out = (u16*)Cout;
#pragma unroll
    for (int mt = 0; mt < 4; mt++)
#pragma unroll
      for (int nt = 0; nt < 4; nt++)
#pragma unroll
        for (int r = 0; r < 4; r++) {
          int gm = tm + wm + mt * 16 + quad * 4 + r;
          int gn = tn + wn + nt * 16 + l15;
          int b = gm >> 11, t = gm & 2047;
          int h2 = gn >> 6, d = gn & 63;
          size_t idx = (size_t)(h2 >> 4) * 8388608
                     + ((size_t)((b * 16 + (h2 & 15)) * 2048 + t) << 6) + d;
          out[idx] = f2b(acc[mt][nt][r]);
        }
  } else {
    float* out = (float*)Cout;
#pragma unroll
    for (int mt = 0; mt < 4; mt++)
#pragma unroll
      for (int nt = 0; nt < 4; nt++)
#pragma unroll
        for (int r = 0; r < 4; r++) {
          int gm = tm + wm + mt * 16 + quad * 4 + r;
          int gn = tn + wn + nt * 16 + l15;
          out[(size_t)gm * 1024 + gn] = acc[mt][nt][r];
        }
  }
}

// ---------------- V transpose: [B,H,T,Dh] -> [B,H,Dh,T] ----------------
__global__ __launch_bounds__(256) void transpose_v_kernel(
    const u16* __restrict__ V, u16* __restrict__ Vt)
{
  __shared__ __align__(16) u16 Ls[64 * 72];
  const int t0 = blockIdx.x * 64;
  const int bh = blockIdx.y;
  const u16* src = V  + (size_t)bh * (T_ * DH_);
  u16*       dst = Vt + (size_t)bh * (DH_ * T_);
#pragma unroll
  for (int i = 0; i < 2; i++) {
    int c = threadIdx.x + i * 256;
    int row = c >> 3, col = (c & 7) * 8;
    *(uint4*)(&Ls[row * 72 + col]) = *(const uint4*)(src + (size_t)(t0 + row) * DH_ + col);
  }
  __syncthreads();
#pragma unroll
  for (int i = 0; i < 2; i++) {
    int c = threadIdx.x + i * 256;
    int d = c >> 3, tc = (c & 7) * 8;
    u16 tmp[8];
#pragma unroll
    for (int j = 0; j < 8; j++) tmp[j] = Ls[(tc + j) * 72 + d];
    *(uint4*)(dst + (size_t)d * T_ + t0 + tc) = *(uint4*)tmp;
  }
}

// ---------------- causal flash attention, K==Q (reference bug), bf16 MFMA ----------------
// Barrier-free: per-wave 32 q-rows, direct-global K/V fragments, fixed-max softmax.
// Pairing: wave handles 32-row tile i and tile 63-i -> uniform 32-34 k-tiles/wave.
// grid 1024 blocks x 128 threads (2 waves); all 2048 waves co-resident.
__global__ __launch_bounds__(128) void attn_kernel(
    const u16* __restrict__ Q, const u16* __restrict__ Vt, u16* __restrict__ AO)
{
  constexpr int LDP = 72;   // P row stride (u16): 144B rows, 16B-aligned
  __shared__ __align__(16) u16 Ps[2][32 * LDP];

  const int tid  = threadIdx.x;
  const int wave = tid >> 6, lane = tid & 63;
  const int quad = lane >> 4, l15 = lane & 15;
  const int bid  = blockIdx.x;
  const int bh = bid >> 4, u = bid & 15;
  const int b = bh >> 4, h = bh & 15;
  const u16* Qbh = Q  + (size_t)bh * (T_ * DH_);
  const u16* Vbh = Vt + (size_t)bh * (DH_ * T_);
  u16* myP = &Ps[wave][0];
  const int iA = u * 2 + wave;   // 0..31

  const float C1 = 0.18033688f;    // log2(e)/sqrt(64)
  const float C2 = -28.8539008f;   // -20*log2(e)  (fixed max M=20, shift-invariant)

  for (int pass = 0; pass < 2; pass++) {
    const int i   = pass ? (63 - iA) : iA;
    const int q0  = i * 32;
    const int nkb = (i >> 1) + 1;  // k-tiles of 64 keys covering rows q0..q0+31

    bf16x8 qf[2][2];
#pragma unroll
    for (int mt = 0; mt < 2; mt++)
#pragma unroll
      for (int ks = 0; ks < 2; ks++)
        qf[mt][ks] = *(const bf16x8*)(Qbh + (size_t)(q0 + mt * 16 + l15) * DH_ + ks * 32 + quad * 8);

    f32x4 o[2][4] = {};
    float lsum[2][4] = {};

    for (int kb = 0; kb < nkb; kb++) {
      const int k0 = kb * 64;
      // K fragments (B-operand of QK^T wants dh-contiguity = natural layout)
      bf16x8 kf[4][2];
#pragma unroll
      for (int nt = 0; nt < 4; nt++)
#pragma unroll
        for (int ks = 0; ks < 2; ks++)
          kf[nt][ks] = *(const bf16x8*)(Qbh + (size_t)(k0 + nt * 16 + l15) * DH_ + ks * 32 + quad * 8);
      // V fragments (B-operand of PV wants key-contiguity = Vt layout); issue early
      bf16x8 vf[4][2];
#pragma unroll
      for (int dt = 0; dt < 4; dt++)
#pragma unroll
        for (int ks = 0; ks < 2; ks++)
          vf[dt][ks] = *(const bf16x8*)(Vbh + (size_t)(dt * 16 + l15) * T_ + k0 + ks * 32 + quad * 8);

      // S = Q K^T
      f32x4 s[2][4] = {};
#pragma unroll
      for (int ks = 0; ks < 2; ks++)
#pragma unroll
        for (int nt = 0; nt < 4; nt++)
#pragma unroll
          for (int mt = 0; mt < 2; mt++)
            s[mt][nt] = __builtin_amdgcn_mfma_f32_16x16x32_bf16(qf[mt][ks], kf[nt][ks], s[mt][nt], 0, 0, 0);

      // fixed-max softmax: p = exp2(s*scale*log2e - M*log2e); per-lane partial row sums
      const bool diag = (kb == nkb - 1);
#pragma unroll
      for (int mt = 0; mt < 2; mt++)
#pragma unroll
        for (int nt = 0; nt < 4; nt++)
#pragma unroll
          for (int r = 0; r < 4; r++) {
            float p = exp2f(s[mt][nt][r] * C1 + C2);
            if (diag) {
              int qg = q0 + mt * 16 + quad * 4 + r;
              int kg = k0 + nt * 16 + l15;
              p = (kg <= qg) ? p : 0.0f;
            }
            lsum[mt][r] += p;
            myP[(mt * 16 + quad * 4 + r) * LDP + nt * 16 + l15] = f2b(p);
          }

      // O += P V   (P: C-layout -> A-layout via wave-private LDS, no barrier)
#pragma unroll
      for (int ks2 = 0; ks2 < 2; ks2++) {
        bf16x8 pf[2];
#pragma unroll
        for (int mt = 0; mt < 2; mt++)
          pf[mt] = *(const bf16x8*)(&myP[(mt * 16 + l15) * LDP + ks2 * 32 + quad * 8]);
#pragma unroll
        for (int dt = 0; dt < 4; dt++)
#pragma unroll
          for (int mt = 0; mt < 2; mt++)
            o[mt][dt] = __builtin_amdgcn_mfma_f32_16x16x32_bf16(pf[mt], vf[dt][ks2], o[mt][dt], 0, 0, 0);
      }
    }

    // epilogue: reduce row sums across the 16-lane col groups (once per pass)
#pragma unroll
    for (int mt = 0; mt < 2; mt++)
#pragma unroll
      for (int r = 0; r < 4; r++) {
        float v = lsum[mt][r];
#pragma unroll
        for (int off = 1; off < 16; off <<= 1) v += __shfl_xor(v, off, 64);
        float rl = 1.0f / v;
        int t = q0 + mt * 16 + quad * 4 + r;
#pragma unroll
        for (int dt = 0; dt < 4; dt++)
          AO[((size_t)(b * T_ + t)) * C_ + h * DH_ + dt * 16 + l15] = f2b(o[mt][dt][r] * rl);
      }
  }
}

extern "C" void kernel_launch(void* const* d_in, const int* in_sizes, int n_in,
                              void* d_out, int out_size, void* d_ws, size_t ws_size,
                              hipStream_t stream) {
  (void)in_sizes; (void)n_in; (void)out_size; (void)ws_size;
  const float* x  = (const float*)d_in[0];
  const float* Wq = (const float*)d_in[1];
  // d_in[2] = W_k is unused (reference bug: K uses W_q)
  const float* Wv = (const float*)d_in[3];
  const float* Wo = (const float*)d_in[4];

  // workspace layout (u16 elements); AO reuses Xb's slot (Xb dead after GEMM1)
  u16* Xb  = (u16*)d_ws;            // 8388608  : x bf16 [8192,1024]; later AO [B,T,C]
  u16* AOw = Xb;
  u16* Wqb = Xb  + 8388608;         // 1048576  : W_q bf16
  u16* Wvb = Wqb + 1048576;         // 1048576  : W_v bf16 (adjacent -> fused N=2048 GEMM)
  u16* Wob = Wvb + 1048576;         // 1048576  : W_o bf16
  u16* Qw  = Wob + 1048576;         // 8388608  : Q [B,H,T,Dh] bf16
  u16* Vw  = Qw  + 8388608;         // 8388608  : V [B,H,T,Dh] bf16 (adjacent to Q)
  u16* Vtw = Vw  + 8388608;         // 8388608  : V^T [B,H,Dh,T] bf16
  // total 73,400,320 bytes

  cast_bf16_kernel<<<8192, 256, 0, stream>>>(x,  Xb,  8388608);
  cast_bf16_kernel<<<1024, 256, 0, stream>>>(Wq, Wqb, 1048576);
  cast_bf16_kernel<<<1024, 256, 0, stream>>>(Wv, Wvb, 1048576);
  cast_bf16_kernel<<<1024, 256, 0, stream>>>(Wo, Wob, 1048576);

  // fused Q+V projection: B = [Wq; Wv] (2048 x 1024), scatter epilogue
  gemm_bt_kernel<<<dim3(64, 16), 256, 0, stream>>>(Xb, Wqb, (void*)Qw, 0);

  transpose_v_kernel<<<dim3(32, 64), 256, 0, stream>>>(Vw, Vtw);

  attn_kernel<<<1024, 128, 0, stream>>>(Qw, Vtw, AOw);

  // output projection -> fp32 d_out
  gemm_bt_kernel<<<dim3(64, 8), 256, 0, stream>>>(AOw, Wob, d_out, 1);
}

// Round 3
// 311.641 us; speedup vs baseline: 1.5229x; 1.0025x over previous
//
#include <hip/hip_runtime.h>
#include <hip/hip_bf16.h>

typedef unsigned short u16;
typedef __attribute__((ext_vector_type(8))) short bf16x8;
typedef __attribute__((ext_vector_type(4))) float f32x4;

#define B_  4
#define T_  2048
#define C_  1024
#define H_  16
#define DH_ 64
#define M_  (B_*T_)   // 8192

// async global->LDS, 16B per lane; LDS dest = wave-uniform base + lane*16
#define GLDS16(g, l) __builtin_amdgcn_global_load_lds( \
    (const __attribute__((address_space(1))) void*)(g), \
    (__attribute__((address_space(3))) void*)(l), 16, 0, 0)

__device__ __forceinline__ u16 f2b(float f) {
  union { __hip_bfloat16 h; u16 u; } cv;
  cv.h = __float2bfloat16(f);
  return cv.u;
}

// ---------------- fp32 -> bf16 cast, 4 elems/thread ----------------
__global__ void cast_bf16_kernel(const float* __restrict__ in, u16* __restrict__ out, int n) {
  int i = (blockIdx.x * blockDim.x + threadIdx.x) * 4;
  if (i >= n) return;
  float4 v = *(const float4*)(in + i);
  unsigned lo = (unsigned)f2b(v.x) | ((unsigned)f2b(v.y) << 16);
  unsigned hi = (unsigned)f2b(v.z) | ((unsigned)f2b(v.w) << 16);
  uint2 p; p.x = lo; p.y = hi;
  *(uint2*)(out + i) = p;
}

// ---------------- GEMM: C[m,n] = sum_k A[m,k] * B[n,k]  (B row-major [N,K]) ----------------
// m97-style: 128x128 tile, BK=32, global_load_lds width-16 staging, unpadded LDS (64B rows).
// mode 0: bf16 scatter; N=2048 = [Wq;Wv]: Q-half -> [B,H,T,Dh], V-half -> Vt [B,H,Dh,T]
// mode 1: fp32 row-major [M,1024]
__global__ __launch_bounds__(256) void gemm_bt_kernel(
    const u16* __restrict__ A, const u16* __restrict__ Bm,
    void* __restrict__ Cout, int mode)
{
  constexpr int K = 1024;
  __shared__ __align__(16) u16 As[128 * 32];
  __shared__ __align__(16) u16 Bs[128 * 32];

  const int tid  = threadIdx.x;
  const int wave = tid >> 6, lane = tid & 63;
  const int quad = lane >> 4, l15 = lane & 15;
  const int wm = (wave >> 1) * 64, wn = (wave & 1) * 64;
  const int tm = blockIdx.x * 128, tn = blockIdx.y * 128;

  // staged 16B chunk indices: chunk c -> LDS elems [c*8, c*8+8), row=c>>2, col=(c&3)*8
  const int c0 = wave * 128 + lane;
  const int c1 = c0 + 64;
  const int r0 = c0 >> 2, o0 = (c0 & 3) * 8;
  const int r1 = c1 >> 2, o1 = (c1 & 3) * 8;
  u16* ldsA0 = &As[wave * 1024];
  u16* ldsA1 = &As[wave * 1024 + 512];
  u16* ldsB0 = &Bs[wave * 1024];
  u16* ldsB1 = &Bs[wave * 1024 + 512];

  f32x4 acc[4][4] = {};

  for (int k0 = 0; k0 < K; k0 += 32) {
    GLDS16(A  + (size_t)(tm + r0) * K + k0 + o0, ldsA0);
    GLDS16(A  + (size_t)(tm + r1) * K + k0 + o1, ldsA1);
    GLDS16(Bm + (size_t)(tn + r0) * K + k0 + o0, ldsB0);
    GLDS16(Bm + (size_t)(tn + r1) * K + k0 + o1, ldsB1);
    __syncthreads();

    bf16x8 af[4], bfr[4];
#pragma unroll
    for (int t = 0; t < 4; t++) {
      af[t]  = *(const bf16x8*)(&As[(wm + t * 16 + l15) * 32 + quad * 8]);
      bfr[t] = *(const bf16x8*)(&Bs[(wn + t * 16 + l15) * 32 + quad * 8]);
    }
#pragma unroll
    for (int mt = 0; mt < 4; mt++)
#pragma unroll
      for (int nt = 0; nt < 4; nt++)
        acc[mt][nt] = __builtin_amdgcn_mfma_f32_16x16x32_bf16(af[mt], bfr[nt], acc[mt][nt], 0, 0, 0);
    __syncthreads();
  }

  if (mode == 0) {
    u16* out = (u16*)Cout;
    if (tn < 1024) {
      // Q half -> [B,H,T,Dh]
#pragma unroll
      for (int mt = 0; mt < 4; mt++)
#pragma unroll
        for (int nt = 0; nt < 4; nt++)
#pragma unroll
          for (int r = 0; r < 4; r++) {
            int gm = tm + wm + mt * 16 + quad * 4 + r;
            int gn = tn + wn + nt * 16 + l15;
            int b = gm >> 11, t = gm & 2047;
            int h = gn >> 6, d = gn & 63;
            out[((size_t)((b * 16 + h) * 2048 + t) << 6) + d] = f2b(acc[mt][nt][r]);
          }
    } else {
      // V half -> Vt [B,H,Dh,T] (fused transpose); r-loop is contiguous in t -> pack 4
#pragma unroll
      for (int mt = 0; mt < 4; mt++)
#pragma unroll
        for (int nt = 0; nt < 4; nt++) {
          int gm0 = tm + wm + mt * 16 + quad * 4;
          int gn  = tn - 1024 + wn + nt * 16 + l15;
          int b = gm0 >> 11, t0 = gm0 & 2047;
          int h = gn >> 6, d = gn & 63;
          alignas(8) u16 tmp[4];
#pragma unroll
          for (int r = 0; r < 4; r++) tmp[r] = f2b(acc[mt][nt][r]);
          *(ushort4*)(out + 8388608 + (((size_t)(b * 16 + h) * 64 + d) << 11) + t0)
              = *(const ushort4*)tmp;
        }
    }
  } else {
    float* out = (float*)Cout;
#pragma unroll
    for (int mt = 0; mt < 4; mt++)
#pragma unroll
      for (int nt = 0; nt < 4; nt++)
#pragma unroll
        for (int r = 0; r < 4; r++) {
          int gm = tm + wm + mt * 16 + quad * 4 + r;
          int gn = tn + wn + nt * 16 + l15;
          out[(size_t)gm * 1024 + gn] = acc[mt][nt][r];
        }
  }
}

// ---------------- causal flash attention, K==Q (reference bug), bf16 MFMA ----------------
// Barrier-free, fixed-max softmax, XCD-swizzled blocks, register-pipelined kf prefetch.
// grid 1024 x 128 (2 waves); wave owns 32 q-rows, pairing (i, 63-i) -> uniform load.
__global__ __launch_bounds__(128, 2) void attn_kernel(
    const u16* __restrict__ Q, const u16* __restrict__ Vt, u16* __restrict__ AO)
{
  constexpr int LDP = 72;
  __shared__ __align__(16) u16 Ps[2][32 * LDP];

  const int tid  = threadIdx.x;
  const int wave = tid >> 6, lane = tid & 63;
  const int quad = lane >> 4, l15 = lane & 15;
  const int bid  = blockIdx.x;
  // XCD swizzle (assumes round-robin bid%8 -> XCD): XCD x serves bh in [8x, 8x+8)
  const int bh = (bid & 7) * 8 + ((bid >> 3) & 7);
  const int u  = bid >> 6;
  const int b = bh >> 4, h = bh & 15;
  const u16* Qbh = Q  + (size_t)bh * (T_ * DH_);
  const u16* Vbh = Vt + (size_t)bh * (DH_ * T_);
  u16* myP = &Ps[wave][0];
  const int iA = u * 2 + wave;   // 0..31

  const float C1 = 0.18033688f;    // log2(e)/sqrt(64)
  const float C2 = -28.8539008f;   // -20*log2(e)  (fixed max M=20, shift-invariant)

  for (int pass = 0; pass < 2; pass++) {
    const int i   = pass ? (63 - iA) : iA;
    const int q0  = i * 32;
    const int nkb = (i >> 1) + 1;

    bf16x8 qf[2][2];
#pragma unroll
    for (int mt = 0; mt < 2; mt++)
#pragma unroll
      for (int ks = 0; ks < 2; ks++)
        qf[mt][ks] = *(const bf16x8*)(Qbh + (size_t)(q0 + mt * 16 + l15) * DH_ + ks * 32 + quad * 8);

    f32x4 o[2][4] = {};
    float lsum[2][4] = {};

    bf16x8 kfA[4][2], kfB[4][2], vf[4][2];

    auto load_kf = [&](int k0, bf16x8 (&kf)[4][2]) {
#pragma unroll
      for (int nt = 0; nt < 4; nt++)
#pragma unroll
        for (int ks = 0; ks < 2; ks++)
          kf[nt][ks] = *(const bf16x8*)(Qbh + (size_t)(k0 + nt * 16 + l15) * DH_ + ks * 32 + quad * 8);
    };
    auto load_vf = [&](int k0) {
#pragma unroll
      for (int dt = 0; dt < 4; dt++)
#pragma unroll
        for (int ks = 0; ks < 2; ks++)
          vf[dt][ks] = *(const bf16x8*)(Vbh + (size_t)(dt * 16 + l15) * T_ + k0 + ks * 32 + quad * 8);
    };
    auto compute = [&](int kb, bf16x8 (&kf)[4][2]) {
      const int k0 = kb * 64;
      f32x4 s[2][4] = {};
#pragma unroll
      for (int ks = 0; ks < 2; ks++)
#pragma unroll
        for (int nt = 0; nt < 4; nt++)
#pragma unroll
          for (int mt = 0; mt < 2; mt++)
            s[mt][nt] = __builtin_amdgcn_mfma_f32_16x16x32_bf16(qf[mt][ks], kf[nt][ks], s[mt][nt], 0, 0, 0);

      const bool diag = (kb == nkb - 1);
#pragma unroll
      for (int mt = 0; mt < 2; mt++)
#pragma unroll
        for (int nt = 0; nt < 4; nt++)
#pragma unroll
          for (int r = 0; r < 4; r++) {
            float p = exp2f(s[mt][nt][r] * C1 + C2);
            if (diag) {
              int qg = q0 + mt * 16 + quad * 4 + r;
              int kg = k0 + nt * 16 + l15;
              p = (kg <= qg) ? p : 0.0f;
            }
            lsum[mt][r] += p;
            myP[(mt * 16 + quad * 4 + r) * LDP + nt * 16 + l15] = f2b(p);
          }

      // O += P V  (P C-layout -> A-layout via wave-private LDS, no barrier)
#pragma unroll
      for (int ks2 = 0; ks2 < 2; ks2++) {
        bf16x8 pf[2];
#pragma unroll
        for (int mt = 0; mt < 2; mt++)
          pf[mt] = *(const bf16x8*)(&myP[(mt * 16 + l15) * LDP + ks2 * 32 + quad * 8]);
#pragma unroll
        for (int dt = 0; dt < 4; dt++)
#pragma unroll
          for (int mt = 0; mt < 2; mt++)
            o[mt][dt] = __builtin_amdgcn_mfma_f32_16x16x32_bf16(pf[mt], vf[dt][ks2], o[mt][dt], 0, 0, 0);
      }
    };

    load_kf(0, kfA);
    int kb = 0;
    while (true) {
      load_vf(kb * 64);
      if (kb + 1 < nkb) load_kf((kb + 1) * 64, kfB);
      compute(kb, kfA);
      if (++kb >= nkb) break;
      load_vf(kb * 64);
      if (kb + 1 < nkb) load_kf((kb + 1) * 64, kfA);
      compute(kb, kfB);
      if (++kb >= nkb) break;
    }

    // epilogue: reduce row sums across 16-lane col groups, normalize, store
#pragma unroll
    for (int mt = 0; mt < 2; mt++)
#pragma unroll
      for (int r = 0; r < 4; r++) {
        float v = lsum[mt][r];
#pragma unroll
        for (int off = 1; off < 16; off <<= 1) v += __shfl_xor(v, off, 64);
        float rl = 1.0f / v;
        int t = q0 + mt * 16 + quad * 4 + r;
#pragma unroll
        for (int dt = 0; dt < 4; dt++)
          AO[((size_t)(b * T_ + t)) * C_ + h * DH_ + dt * 16 + l15] = f2b(o[mt][dt][r] * rl);
      }
  }
}

extern "C" void kernel_launch(void* const* d_in, const int* in_sizes, int n_in,
                              void* d_out, int out_size, void* d_ws, size_t ws_size,
                              hipStream_t stream) {
  (void)in_sizes; (void)n_in; (void)out_size; (void)ws_size;
  const float* x  = (const float*)d_in[0];
  const float* Wq = (const float*)d_in[1];
  // d_in[2] = W_k unused (reference bug: K uses W_q)
  const float* Wv = (const float*)d_in[3];
  const float* Wo = (const float*)d_in[4];

  // workspace (u16 elems); AO reuses Xb slot (dead after gemm1)
  u16* Xb  = (u16*)d_ws;            // 8388608 : x bf16; later AO [B,T,C]
  u16* AOw = Xb;
  u16* Wqb = Xb  + 8388608;         // 1048576
  u16* Wvb = Wqb + 1048576;         // 1048576 (adjacent -> fused N=2048 GEMM)
  u16* Wob = Wvb + 1048576;         // 1048576
  u16* Qw  = Wob + 1048576;         // 8388608 : Q [B,H,T,Dh]
  u16* Vtw = Qw  + 8388608;         // 8388608 : Vt [B,H,Dh,T] (gemm1 writes directly)
  // total 54,525,952 bytes

  cast_bf16_kernel<<<8192, 256, 0, stream>>>(x,  Xb,  8388608);
  cast_bf16_kernel<<<1024, 256, 0, stream>>>(Wq, Wqb, 1048576);
  cast_bf16_kernel<<<1024, 256, 0, stream>>>(Wv, Wvb, 1048576);
  cast_bf16_kernel<<<1024, 256, 0, stream>>>(Wo, Wob, 1048576);

  // fused Q+V projection; V half written pre-transposed (Vt base = Qw + 8388608)
  gemm_bt_kernel<<<dim3(64, 16), 256, 0, stream>>>(Xb, Wqb, (void*)Qw, 0);

  attn_kernel<<<1024, 128, 0, stream>>>(Qw, Vtw, AOw);

  gemm_bt_kernel<<<dim3(64, 8), 256, 0, stream>>>(AOw, Wob, d_out, 1);
}